// Round 2
// baseline (195.127 us; speedup 1.0000x reference)
//
#include <hip/hip_runtime.h>
#include <hip/hip_cooperative_groups.h>
#include <math.h>

namespace cg = cooperative_groups;

#define N_INC   12288
#define N_EDGES 6144
#define N_TRI   4096
#define CAP_T   32   // max triangle-group size (expected 3, Poisson tail << 32)
#define CAP_E   16   // max edge-segment size (expected 2)
#define BLK     256
#define GRD     48   // 48*256 = 12288 = one thread per incidence

struct Params {
    const float* ef; const int* eid; const int* tri;
    const float *Wq, *bq, *Wk, *bk, *Wv, *bv;
    const float *W1, *b1, *ln1g, *ln1b, *rmsw, *Wr, *br, *ln2g, *ln2b, *W2, *b2, *W3, *b3;
    float* out;
    float *kbuf, *vbuf, *logits;
    int *tri_cnt, *tri_bkt, *edge_cnt, *edge_bkt;
};

__device__ __forceinline__ float gelu_exact(float x) {
    return 0.5f * x * (1.0f + erff(x * 0.70710678118654752f));
}

__global__ void __launch_bounds__(BLK)
fused_kernel(Params p) {
    cg::grid_group grid = cg::this_grid();
    const int gid = blockIdx.x * BLK + threadIdx.x;

    // ---------- P0: zero bucket counters (ws is poisoned each call) ----------
    if (gid < N_TRI)   p.tri_cnt[gid]  = 0;
    if (gid < N_EDGES) p.edge_cnt[gid] = 0;
    grid.sync();

    // ---------- P1: QKV projection + bucket fill ----------
    float qi[8];
    if (gid < N_INC) {
        float x0 = p.ef[gid * 2], x1 = p.ef[gid * 2 + 1];
#pragma unroll
        for (int d = 0; d < 8; d++) {
            qi[d]               = p.Wq[d * 2] * x0 + p.Wq[d * 2 + 1] * x1 + p.bq[d];
            p.kbuf[gid * 8 + d] = p.Wk[d * 2] * x0 + p.Wk[d * 2 + 1] * x1 + p.bk[d];
            p.vbuf[gid * 8 + d] = p.Wv[d * 2] * x0 + p.Wv[d * 2 + 1] * x1 + p.bv[d];
        }
        int t = p.tri[gid];
        int s = atomicAdd(&p.tri_cnt[t], 1);
        if (s < CAP_T) p.tri_bkt[t * CAP_T + s] = gid;
        int e = p.eid[gid];
        s = atomicAdd(&p.edge_cnt[e], 1);
        if (s < CAP_E) p.edge_bkt[e * CAP_E + s] = gid;
    }
    grid.sync();

    // ---------- P2: sparse attention over triangle group + MLP -> logit ----------
    if (gid < N_INC) {
        int t = p.tri[gid];
        int n = min(p.tri_cnt[t], CAP_T);

        float m = -1e30f, l = 0.f, acc[8];
#pragma unroll
        for (int d = 0; d < 8; d++) acc[d] = 0.f;

        for (int s = 0; s < n; s++) {
            int j = p.tri_bkt[t * CAP_T + s];
            float sc = 0.f;
#pragma unroll
            for (int d = 0; d < 8; d++) sc += qi[d] * p.kbuf[j * 8 + d];
            sc *= 0.35355339059327373f;  // 1/sqrt(8)
            float nm = fmaxf(m, sc);
            float scale = expf(m - nm);
            float w = expf(sc - nm);
            l = l * scale + w;
#pragma unroll
            for (int d = 0; d < 8; d++) acc[d] = acc[d] * scale + w * p.vbuf[j * 8 + d];
            m = nm;
        }
        float inv_l = 1.f / l;
        float att[8];
#pragma unroll
        for (int d = 0; d < 8; d++) att[d] = acc[d] * inv_l;

        // ---- MLP (weights wave-uniform -> scalar loads) ----
        float h[32];
#pragma unroll
        for (int o = 0; o < 32; o++) {
            float a = p.b1[o];
#pragma unroll
            for (int d = 0; d < 8; d++) a += p.W1[o * 8 + d] * att[d];
            h[o] = a;
        }
        // LayerNorm 1
        {
            float mu = 0.f;
#pragma unroll
            for (int o = 0; o < 32; o++) mu += h[o];
            mu *= (1.f / 32.f);
            float var = 0.f;
#pragma unroll
            for (int o = 0; o < 32; o++) { float d = h[o] - mu; var += d * d; }
            var *= (1.f / 32.f);
            float is = 1.f / sqrtf(var + 1e-5f);
#pragma unroll
            for (int o = 0; o < 32; o++) h[o] = (h[o] - mu) * is * p.ln1g[o] + p.ln1b[o];
        }
#pragma unroll
        for (int o = 0; o < 32; o++) h[o] = gelu_exact(h[o]);
        // ResBlock: h += relu(Wr @ rmsnorm(h) + br)
        {
            float ss = 0.f;
#pragma unroll
            for (int o = 0; o < 32; o++) ss += h[o] * h[o];
            float rms = sqrtf(ss * (1.f / 32.f));
            float ir = 1.f / (rms + 1e-6f);
            float hn[32];
#pragma unroll
            for (int o = 0; o < 32; o++) hn[o] = h[o] * ir * p.rmsw[o];
#pragma unroll
            for (int o = 0; o < 32; o++) {
                float a = p.br[o];
#pragma unroll
                for (int in = 0; in < 32; in++) a += p.Wr[o * 32 + in] * hn[in];
                h[o] += fmaxf(a, 0.f);
            }
        }
        // LayerNorm 2
        {
            float mu = 0.f;
#pragma unroll
            for (int o = 0; o < 32; o++) mu += h[o];
            mu *= (1.f / 32.f);
            float var = 0.f;
#pragma unroll
            for (int o = 0; o < 32; o++) { float d = h[o] - mu; var += d * d; }
            var *= (1.f / 32.f);
            float is = 1.f / sqrtf(var + 1e-5f);
#pragma unroll
            for (int o = 0; o < 32; o++) h[o] = (h[o] - mu) * is * p.ln2g[o] + p.ln2b[o];
        }
        // Linear 32->16 + GELU
        float h2[16];
#pragma unroll
        for (int o = 0; o < 16; o++) {
            float a = p.b2[o];
#pragma unroll
            for (int in = 0; in < 32; in++) a += p.W2[o * 32 + in] * h[in];
            h2[o] = gelu_exact(a);
        }
        // Linear 16->1
        float lg = p.b3[0];
#pragma unroll
        for (int in = 0; in < 16; in++) lg += p.W3[in] * h2[in];

        p.logits[gid] = lg;
    }
    grid.sync();

    // ---------- P3: per-edge gather softmax ----------
    if (gid < N_EDGES) {
        int n = min(p.edge_cnt[gid], CAP_E);
        if (n > 0) {
            const int* bkt = &p.edge_bkt[gid * CAP_E];
            float mx = -1e30f;
            for (int s = 0; s < n; s++) mx = fmaxf(mx, p.logits[bkt[s]]);
            float sum = 0.f;
            for (int s = 0; s < n; s++) sum += expf(p.logits[bkt[s]] - mx);
            float inv = 1.f / sum;
            for (int s = 0; s < n; s++) {
                int idx = bkt[s];
                p.out[idx] = expf(p.logits[idx] - mx) * inv;
            }
        }
    }
}

extern "C" void kernel_launch(void* const* d_in, const int* in_sizes, int n_in,
                              void* d_out, int out_size, void* d_ws, size_t ws_size,
                              hipStream_t stream) {
    Params p;
    p.ef   = (const float*)d_in[0];
    p.eid  = (const int*)d_in[1];
    p.tri  = (const int*)d_in[2];
    p.Wq   = (const float*)d_in[3];  p.bq   = (const float*)d_in[4];
    p.Wk   = (const float*)d_in[5];  p.bk   = (const float*)d_in[6];
    p.Wv   = (const float*)d_in[7];  p.bv   = (const float*)d_in[8];
    p.W1   = (const float*)d_in[9];  p.b1   = (const float*)d_in[10];
    p.ln1g = (const float*)d_in[11]; p.ln1b = (const float*)d_in[12];
    p.rmsw = (const float*)d_in[13];
    p.Wr   = (const float*)d_in[14]; p.br   = (const float*)d_in[15];
    p.ln2g = (const float*)d_in[16]; p.ln2b = (const float*)d_in[17];
    p.W2   = (const float*)d_in[18]; p.b2   = (const float*)d_in[19];
    p.W3   = (const float*)d_in[20]; p.b3   = (const float*)d_in[21];
    p.out  = (float*)d_out;

    float* ws  = (float*)d_ws;
    p.kbuf     = ws;                       // N_INC*8
    p.vbuf     = p.kbuf + N_INC * 8;       // N_INC*8
    p.logits   = p.vbuf + N_INC * 8;       // N_INC
    p.tri_cnt  = (int*)(p.logits + N_INC); // N_TRI
    p.tri_bkt  = p.tri_cnt + N_TRI;        // N_TRI*CAP_T
    p.edge_cnt = p.tri_bkt + N_TRI * CAP_T;    // N_EDGES
    p.edge_bkt = p.edge_cnt + N_EDGES;         // N_EDGES*CAP_E

    void* kargs[] = { (void*)&p };
    hipLaunchCooperativeKernel((const void*)fused_kernel, dim3(GRD), dim3(BLK),
                               kargs, 0, stream);
}

// Round 3
// 129.756 us; speedup vs baseline: 1.5038x; 1.5038x over previous
//
#include <hip/hip_runtime.h>
#include <math.h>

#define N_INC   12288
#define N_EDGES 6144
#define N_TRI   4096
#define CAP_T   32   // max triangle-group size (Poisson mean 3)
#define CAP_E   16   // max edge-segment size (Poisson mean 2)

__device__ __forceinline__ float gelu_exact(float x) {
    return 0.5f * x * (1.0f + erff(x * 0.70710678118654752f));
}

// ---------------- K1: QKV projection + bucket fill ----------------
__global__ void __launch_bounds__(256) k_qkv_fill(
    const float* __restrict__ ef, const int* __restrict__ eid, const int* __restrict__ tri,
    const float* __restrict__ Wq, const float* __restrict__ bq,
    const float* __restrict__ Wk, const float* __restrict__ bk,
    const float* __restrict__ Wv, const float* __restrict__ bv,
    float* __restrict__ q, float* __restrict__ k, float* __restrict__ v,
    int* __restrict__ tri_cnt, int* __restrict__ tri_bkt,
    int* __restrict__ edge_cnt, int* __restrict__ edge_bkt)
{
    int i = blockIdx.x * 256 + threadIdx.x;
    if (i >= N_INC) return;
    float2 x = ((const float2*)ef)[i];
    float qq[8], kk[8], vv[8];
#pragma unroll
    for (int d = 0; d < 8; d++) {
        qq[d] = fmaf(Wq[d*2], x.x, fmaf(Wq[d*2+1], x.y, bq[d]));
        kk[d] = fmaf(Wk[d*2], x.x, fmaf(Wk[d*2+1], x.y, bk[d]));
        vv[d] = fmaf(Wv[d*2], x.x, fmaf(Wv[d*2+1], x.y, bv[d]));
    }
    ((float4*)q)[i*2+0] = make_float4(qq[0],qq[1],qq[2],qq[3]);
    ((float4*)q)[i*2+1] = make_float4(qq[4],qq[5],qq[6],qq[7]);
    ((float4*)k)[i*2+0] = make_float4(kk[0],kk[1],kk[2],kk[3]);
    ((float4*)k)[i*2+1] = make_float4(kk[4],kk[5],kk[6],kk[7]);
    ((float4*)v)[i*2+0] = make_float4(vv[0],vv[1],vv[2],vv[3]);
    ((float4*)v)[i*2+1] = make_float4(vv[4],vv[5],vv[6],vv[7]);

    int t = tri[i];
    int s = atomicAdd(&tri_cnt[t], 1);
    if (s < CAP_T) tri_bkt[t * CAP_T + s] = i;
    int e = eid[i];
    s = atomicAdd(&edge_cnt[e], 1);
    if (s < CAP_E) edge_bkt[e * CAP_E + s] = i;
}

// ---------------- K2: attention + MLP -> logits (weights in LDS) ----------------
__global__ void __launch_bounds__(256) k_main(
    const float* __restrict__ q, const float* __restrict__ kbuf, const float* __restrict__ vbuf,
    const int* __restrict__ tri, const int* __restrict__ tri_cnt, const int* __restrict__ tri_bkt,
    const float* __restrict__ W1, const float* __restrict__ b1,
    const float* __restrict__ ln1g, const float* __restrict__ ln1b,
    const float* __restrict__ rmsw,
    const float* __restrict__ Wr, const float* __restrict__ br,
    const float* __restrict__ ln2g, const float* __restrict__ ln2b,
    const float* __restrict__ W2, const float* __restrict__ b2,
    const float* __restrict__ W3, const float* __restrict__ b3,
    float* __restrict__ logits)
{
    __shared__ float sW1[256], sb1[32], sg1[32], sB1[32], srw[32];
    __shared__ float sWr[1024], sbr[32], sg2[32], sB2[32];
    __shared__ float sW2[512], sb2[16], sW3[16];

    const int tid = threadIdx.x;
#define CP(dst, src, len) for (int x_ = tid; x_ < (len); x_ += 256) dst[x_] = src[x_];
    CP(sW1, W1, 256) CP(sb1, b1, 32) CP(sg1, ln1g, 32) CP(sB1, ln1b, 32) CP(srw, rmsw, 32)
    CP(sWr, Wr, 1024) CP(sbr, br, 32) CP(sg2, ln2g, 32) CP(sB2, ln2b, 32)
    CP(sW2, W2, 512) CP(sb2, b2, 16) CP(sW3, W3, 16)
#undef CP
    __syncthreads();

    int i = blockIdx.x * 256 + tid;
    if (i >= N_INC) return;

    float qi[8];
    {
        float4 qa = ((const float4*)q)[i*2+0];
        float4 qb = ((const float4*)q)[i*2+1];
        qi[0]=qa.x; qi[1]=qa.y; qi[2]=qa.z; qi[3]=qa.w;
        qi[4]=qb.x; qi[5]=qb.y; qi[6]=qb.z; qi[7]=qb.w;
    }

    int t = tri[i];
    int n = min(tri_cnt[t], CAP_T);
    const int* bkt = tri_bkt + t * CAP_T;

    float m = -1e30f, l = 0.f, acc[8];
#pragma unroll
    for (int d = 0; d < 8; d++) acc[d] = 0.f;

    for (int p0 = 0; p0 < n; p0 += 4) {
        int4 jv = *(const int4*)(bkt + p0);
        int jj[4] = { jv.x, jv.y, jv.z, jv.w };
        int j0 = jv.x;
        float sc[4], vl[4][8];
#pragma unroll
        for (int u = 0; u < 4; u++) {
            int j = (p0 + u < n) ? jj[u] : j0;
            float4 ka = ((const float4*)(kbuf + j*8))[0];
            float4 kb = ((const float4*)(kbuf + j*8))[1];
            float s8 = qi[0]*ka.x + qi[1]*ka.y + qi[2]*ka.z + qi[3]*ka.w
                     + qi[4]*kb.x + qi[5]*kb.y + qi[6]*kb.z + qi[7]*kb.w;
            sc[u] = (p0 + u < n) ? s8 * 0.35355339059327373f : -1e30f;
            float4 va = ((const float4*)(vbuf + j*8))[0];
            float4 vb = ((const float4*)(vbuf + j*8))[1];
            vl[u][0]=va.x; vl[u][1]=va.y; vl[u][2]=va.z; vl[u][3]=va.w;
            vl[u][4]=vb.x; vl[u][5]=vb.y; vl[u][6]=vb.z; vl[u][7]=vb.w;
        }
        float cm = fmaxf(fmaxf(sc[0], sc[1]), fmaxf(sc[2], sc[3]));
        float w0 = expf(sc[0]-cm), w1 = expf(sc[1]-cm);
        float w2 = expf(sc[2]-cm), w3 = expf(sc[3]-cm);
        float cl = w0 + w1 + w2 + w3;
        float nm = fmaxf(m, cm);
        float sa = expf(m - nm), sb = expf(cm - nm);
        l = l * sa + cl * sb;
#pragma unroll
        for (int d = 0; d < 8; d++)
            acc[d] = acc[d]*sa + sb*(w0*vl[0][d] + w1*vl[1][d] + w2*vl[2][d] + w3*vl[3][d]);
        m = nm;
    }
    float inv_l = 1.f / l;
    float att[8];
#pragma unroll
    for (int d = 0; d < 8; d++) att[d] = acc[d] * inv_l;

    // ---- MLP (weights from LDS, uniform broadcast reads) ----
    float h[32];
#pragma unroll
    for (int o = 0; o < 32; o++) {
        float a = sb1[o];
#pragma unroll
        for (int d = 0; d < 8; d++) a += sW1[o*8+d] * att[d];
        h[o] = a;
    }
    {   // LayerNorm 1
        float mu = 0.f;
#pragma unroll
        for (int o = 0; o < 32; o++) mu += h[o];
        mu *= (1.f/32.f);
        float var = 0.f;
#pragma unroll
        for (int o = 0; o < 32; o++) { float d = h[o]-mu; var += d*d; }
        var *= (1.f/32.f);
        float is = 1.f / sqrtf(var + 1e-5f);
#pragma unroll
        for (int o = 0; o < 32; o++) h[o] = (h[o]-mu)*is*sg1[o] + sB1[o];
    }
#pragma unroll
    for (int o = 0; o < 32; o++) h[o] = gelu_exact(h[o]);
    {   // ResBlock: h += relu(Wr @ rmsnorm(h) + br)
        float ss = 0.f;
#pragma unroll
        for (int o = 0; o < 32; o++) ss += h[o]*h[o];
        float rms = sqrtf(ss * (1.f/32.f));
        float ir = 1.f / (rms + 1e-6f);
        float hn[32];
#pragma unroll
        for (int o = 0; o < 32; o++) hn[o] = h[o]*ir*srw[o];
#pragma unroll
        for (int o = 0; o < 32; o++) {
            float a = sbr[o];
#pragma unroll
            for (int in = 0; in < 32; in++) a += sWr[o*32+in] * hn[in];
            h[o] += fmaxf(a, 0.f);
        }
    }
    {   // LayerNorm 2
        float mu = 0.f;
#pragma unroll
        for (int o = 0; o < 32; o++) mu += h[o];
        mu *= (1.f/32.f);
        float var = 0.f;
#pragma unroll
        for (int o = 0; o < 32; o++) { float d = h[o]-mu; var += d*d; }
        var *= (1.f/32.f);
        float is = 1.f / sqrtf(var + 1e-5f);
#pragma unroll
        for (int o = 0; o < 32; o++) h[o] = (h[o]-mu)*is*sg2[o] + sB2[o];
    }
    float h2[16];
#pragma unroll
    for (int o = 0; o < 16; o++) {
        float a = sb2[o];
#pragma unroll
        for (int in = 0; in < 32; in++) a += sW2[o*32+in] * h[in];
        h2[o] = gelu_exact(a);
    }
    float lg = b3[0];
#pragma unroll
    for (int in = 0; in < 16; in++) lg += sW3[in] * h2[in];

    logits[i] = lg;
}

// ---------------- K3: per-edge gather softmax (fully unrolled, predicated) ----------------
__global__ void __launch_bounds__(256) k_edge_softmax(
    const float* __restrict__ logits, const int* __restrict__ edge_cnt,
    const int* __restrict__ edge_bkt, float* __restrict__ out)
{
    int e = blockIdx.x * 256 + threadIdx.x;
    if (e >= N_EDGES) return;
    int n = min(edge_cnt[e], CAP_E);
    if (n == 0) return;
    const int4* bp = (const int4*)(edge_bkt + e * CAP_E);
    int4 b0 = bp[0], b1 = bp[1], b2 = bp[2], b3 = bp[3];
    int idx[16] = { b0.x,b0.y,b0.z,b0.w, b1.x,b1.y,b1.z,b1.w,
                    b2.x,b2.y,b2.z,b2.w, b3.x,b3.y,b3.z,b3.w };
    int i0 = b0.x;
    float lg[16];
#pragma unroll
    for (int u = 0; u < 16; u++) {
        int j = (u < n) ? idx[u] : i0;
        float val = logits[j];
        lg[u] = (u < n) ? val : -1e30f;
    }
    float mx = -1e30f;
#pragma unroll
    for (int u = 0; u < 16; u++) mx = fmaxf(mx, lg[u]);
    float ex[16], sum = 0.f;
#pragma unroll
    for (int u = 0; u < 16; u++) { ex[u] = expf(lg[u] - mx); sum += ex[u]; }
    float inv = 1.f / sum;
#pragma unroll
    for (int u = 0; u < 16; u++) if (u < n) out[idx[u]] = ex[u] * inv;
}

extern "C" void kernel_launch(void* const* d_in, const int* in_sizes, int n_in,
                              void* d_out, int out_size, void* d_ws, size_t ws_size,
                              hipStream_t stream) {
    const float* ef   = (const float*)d_in[0];
    const int*   eid  = (const int*)d_in[1];
    const int*   tri  = (const int*)d_in[2];
    const float* Wq   = (const float*)d_in[3];  const float* bq = (const float*)d_in[4];
    const float* Wk   = (const float*)d_in[5];  const float* bk = (const float*)d_in[6];
    const float* Wv   = (const float*)d_in[7];  const float* bv = (const float*)d_in[8];
    const float* W1   = (const float*)d_in[9];  const float* b1 = (const float*)d_in[10];
    const float* ln1g = (const float*)d_in[11]; const float* ln1b = (const float*)d_in[12];
    const float* rmsw = (const float*)d_in[13];
    const float* Wr   = (const float*)d_in[14]; const float* br = (const float*)d_in[15];
    const float* ln2g = (const float*)d_in[16]; const float* ln2b = (const float*)d_in[17];
    const float* W2   = (const float*)d_in[18]; const float* b2 = (const float*)d_in[19];
    const float* W3   = (const float*)d_in[20]; const float* b3 = (const float*)d_in[21];

    float* ws   = (float*)d_ws;
    float* kbuf = ws;                         // N_INC*8
    float* vbuf = kbuf + N_INC*8;             // N_INC*8
    float* qbuf = vbuf + N_INC*8;             // N_INC*8
    float* logits = qbuf + N_INC*8;           // N_INC
    int* tri_cnt  = (int*)(logits + N_INC);   // N_TRI   } contiguous for
    int* edge_cnt = tri_cnt + N_TRI;          // N_EDGES } one memset
    int* tri_bkt  = edge_cnt + N_EDGES;       // N_TRI*CAP_T
    int* edge_bkt = tri_bkt + N_TRI*CAP_T;    // N_EDGES*CAP_E

    hipMemsetAsync(tri_cnt, 0, (size_t)(N_TRI + N_EDGES) * sizeof(int), stream);

    k_qkv_fill<<<48, 256, 0, stream>>>(ef, eid, tri, Wq, bq, Wk, bk, Wv, bv,
                                       qbuf, kbuf, vbuf,
                                       tri_cnt, tri_bkt, edge_cnt, edge_bkt);
    k_main<<<48, 256, 0, stream>>>(qbuf, kbuf, vbuf, tri, tri_cnt, tri_bkt,
                                   W1, b1, ln1g, ln1b, rmsw, Wr, br, ln2g, ln2b,
                                   W2, b2, W3, b3, logits);
    k_edge_softmax<<<24, 256, 0, stream>>>(logits, edge_cnt, edge_bkt, (float*)d_out);
}

// Round 4
// 116.910 us; speedup vs baseline: 1.6690x; 1.1099x over previous
//
#include <hip/hip_runtime.h>
#include <math.h>

#define N_INC   12288
#define N_EDGES 6144
#define N_TRI   4096
#define CAP_T   32   // max triangle-group size (Poisson mean 3)
#define CAP_E   16   // max edge-segment size (Poisson mean 2)

__device__ __forceinline__ float gelu_exact(float x) {
    return 0.5f * x * (1.0f + erff(x * 0.70710678118654752f));
}

// ---------------- K1: K/V projection + bucket fill (grid exact: 48*256) ----------------
__global__ void __launch_bounds__(256) k_qkv_fill(
    const float* __restrict__ ef, const int* __restrict__ eid, const int* __restrict__ tri,
    const float* __restrict__ Wk, const float* __restrict__ bk,
    const float* __restrict__ Wv, const float* __restrict__ bv,
    float* __restrict__ k, float* __restrict__ v,
    int* __restrict__ tri_cnt, int* __restrict__ tri_bkt,
    int* __restrict__ edge_cnt, int* __restrict__ edge_bkt)
{
    int i = blockIdx.x * 256 + threadIdx.x;
    float2 x = ((const float2*)ef)[i];
    float kk[8], vv[8];
#pragma unroll
    for (int d = 0; d < 8; d++) {
        kk[d] = fmaf(Wk[d*2], x.x, fmaf(Wk[d*2+1], x.y, bk[d]));
        vv[d] = fmaf(Wv[d*2], x.x, fmaf(Wv[d*2+1], x.y, bv[d]));
    }
    ((float4*)k)[i*2+0] = make_float4(kk[0],kk[1],kk[2],kk[3]);
    ((float4*)k)[i*2+1] = make_float4(kk[4],kk[5],kk[6],kk[7]);
    ((float4*)v)[i*2+0] = make_float4(vv[0],vv[1],vv[2],vv[3]);
    ((float4*)v)[i*2+1] = make_float4(vv[4],vv[5],vv[6],vv[7]);

    int t = tri[i];
    int s = atomicAdd(&tri_cnt[t], 1);
    if (s < CAP_T) tri_bkt[t * CAP_T + s] = i;
    int e = eid[i];
    s = atomicAdd(&edge_cnt[e], 1);
    if (s < CAP_E) edge_bkt[e * CAP_E + s] = i;
}

// ---------------- K2: attention + MLP, 4 lanes per row (grid exact: 192*256) ----------------
__global__ void __launch_bounds__(256) k_main(
    const float* __restrict__ ef,
    const float* __restrict__ kbuf, const float* __restrict__ vbuf,
    const int* __restrict__ tri, const int* __restrict__ tri_cnt, const int* __restrict__ tri_bkt,
    const float* __restrict__ Wq, const float* __restrict__ bq,
    const float* __restrict__ W1, const float* __restrict__ b1,
    const float* __restrict__ ln1g, const float* __restrict__ ln1b,
    const float* __restrict__ rmsw,
    const float* __restrict__ Wr, const float* __restrict__ br,
    const float* __restrict__ ln2g, const float* __restrict__ ln2b,
    const float* __restrict__ W2, const float* __restrict__ b2,
    const float* __restrict__ W3, const float* __restrict__ b3,
    float* __restrict__ logits)
{
    __shared__ float sW1[256], sb1[32], sg1[32], sB1[32], srw[32];
    __shared__ float sWr[1024], sbr[32], sg2[32], sB2[32];
    __shared__ float sW2[512], sb2[16], sW3[16];

    const int tid = threadIdx.x;
#define CP(dst, src, len) for (int x_ = tid; x_ < (len); x_ += 256) dst[x_] = src[x_];
    CP(sW1, W1, 256) CP(sb1, b1, 32) CP(sg1, ln1g, 32) CP(sB1, ln1b, 32) CP(srw, rmsw, 32)
    CP(sWr, Wr, 1024) CP(sbr, br, 32) CP(sg2, ln2g, 32) CP(sB2, ln2b, 32)
    CP(sW2, W2, 512) CP(sb2, b2, 16) CP(sW3, W3, 16)
#undef CP
    __syncthreads();

    const int g4 = blockIdx.x * 256 + tid;
    const int i  = g4 >> 2;        // row
    const int lq = tid & 3;        // quad lane
    const int ob = lq * 8;         // my 8 hidden channels [ob, ob+8)

    // ---- q projection (replicated across quad; Wq uniform -> s_loads) ----
    float2 x = ((const float2*)ef)[i];
    float qi[8];
#pragma unroll
    for (int d = 0; d < 8; d++)
        qi[d] = fmaf(Wq[d*2], x.x, fmaf(Wq[d*2+1], x.y, bq[d]));

    // ---- attention over triangle group (replicated across quad) ----
    int t = tri[i];
    int n = min(tri_cnt[t], CAP_T);
    const int* bkt = tri_bkt + t * CAP_T;

    float m = -1e30f, l = 0.f, acc[8];
#pragma unroll
    for (int d = 0; d < 8; d++) acc[d] = 0.f;

    for (int p0 = 0; p0 < n; p0 += 4) {
        int4 jv = *(const int4*)(bkt + p0);
        int jj[4] = { jv.x, jv.y, jv.z, jv.w };
        int j0 = jv.x;
        float sc[4], vl[4][8];
#pragma unroll
        for (int u = 0; u < 4; u++) {
            int j = (p0 + u < n) ? jj[u] : j0;
            float4 ka = ((const float4*)(kbuf + j*8))[0];
            float4 kb = ((const float4*)(kbuf + j*8))[1];
            float s8 = qi[0]*ka.x + qi[1]*ka.y + qi[2]*ka.z + qi[3]*ka.w
                     + qi[4]*kb.x + qi[5]*kb.y + qi[6]*kb.z + qi[7]*kb.w;
            sc[u] = (p0 + u < n) ? s8 * 0.35355339059327373f : -1e30f;
            float4 va = ((const float4*)(vbuf + j*8))[0];
            float4 vb = ((const float4*)(vbuf + j*8))[1];
            vl[u][0]=va.x; vl[u][1]=va.y; vl[u][2]=va.z; vl[u][3]=va.w;
            vl[u][4]=vb.x; vl[u][5]=vb.y; vl[u][6]=vb.z; vl[u][7]=vb.w;
        }
        float cm = fmaxf(fmaxf(sc[0], sc[1]), fmaxf(sc[2], sc[3]));
        float w0 = expf(sc[0]-cm), w1 = expf(sc[1]-cm);
        float w2 = expf(sc[2]-cm), w3 = expf(sc[3]-cm);
        float cl = w0 + w1 + w2 + w3;
        float nm = fmaxf(m, cm);
        float sa = expf(m - nm), sb = expf(cm - nm);
        l = l * sa + cl * sb;
#pragma unroll
        for (int d = 0; d < 8; d++)
            acc[d] = acc[d]*sa + sb*(w0*vl[0][d] + w1*vl[1][d] + w2*vl[2][d] + w3*vl[3][d]);
        m = nm;
    }
    float inv_l = 1.f / l;
    float att[8];
#pragma unroll
    for (int d = 0; d < 8; d++) att[d] = acc[d] * inv_l;

    // ---- MLP: lane-split, 8 channels per lane ----
    float h[8];
#pragma unroll
    for (int oo = 0; oo < 8; oo++) {
        float a = sb1[ob+oo];
#pragma unroll
        for (int d = 0; d < 8; d++) a += sW1[(ob+oo)*8+d] * att[d];
        h[oo] = a;
    }
    {   // LayerNorm 1 (quad-reduced)
        float s = 0.f;
#pragma unroll
        for (int oo = 0; oo < 8; oo++) s += h[oo];
        s += __shfl_xor(s, 1); s += __shfl_xor(s, 2);
        float mu = s * (1.f/32.f);
        float vs = 0.f;
#pragma unroll
        for (int oo = 0; oo < 8; oo++) { float d = h[oo]-mu; vs += d*d; }
        vs += __shfl_xor(vs, 1); vs += __shfl_xor(vs, 2);
        float is = 1.f / sqrtf(vs * (1.f/32.f) + 1e-5f);
#pragma unroll
        for (int oo = 0; oo < 8; oo++) h[oo] = (h[oo]-mu)*is*sg1[ob+oo] + sB1[ob+oo];
    }
#pragma unroll
    for (int oo = 0; oo < 8; oo++) h[oo] = gelu_exact(h[oo]);

    {   // ResBlock: h += relu(Wr @ rmsnorm(h) + br)
        float ss = 0.f;
#pragma unroll
        for (int oo = 0; oo < 8; oo++) ss += h[oo]*h[oo];
        ss += __shfl_xor(ss, 1); ss += __shfl_xor(ss, 2);
        float rms = sqrtf(ss * (1.f/32.f));
        float ir = 1.f / (rms + 1e-6f);
        float hn[8];
#pragma unroll
        for (int oo = 0; oo < 8; oo++) hn[oo] = h[oo]*ir*srw[ob+oo];
        float a[8];
#pragma unroll
        for (int oo = 0; oo < 8; oo++) a[oo] = sbr[ob+oo];
#pragma unroll
        for (int r = 0; r < 4; r++) {
            float g[8];
#pragma unroll
            for (int s8 = 0; s8 < 8; s8++) g[s8] = __shfl(hn[s8], r, 4);
#pragma unroll
            for (int oo = 0; oo < 8; oo++)
#pragma unroll
                for (int s8 = 0; s8 < 8; s8++)
                    a[oo] += sWr[(ob+oo)*32 + r*8 + s8] * g[s8];
        }
#pragma unroll
        for (int oo = 0; oo < 8; oo++) h[oo] += fmaxf(a[oo], 0.f);
    }
    {   // LayerNorm 2 (quad-reduced)
        float s = 0.f;
#pragma unroll
        for (int oo = 0; oo < 8; oo++) s += h[oo];
        s += __shfl_xor(s, 1); s += __shfl_xor(s, 2);
        float mu = s * (1.f/32.f);
        float vs = 0.f;
#pragma unroll
        for (int oo = 0; oo < 8; oo++) { float d = h[oo]-mu; vs += d*d; }
        vs += __shfl_xor(vs, 1); vs += __shfl_xor(vs, 2);
        float is = 1.f / sqrtf(vs * (1.f/32.f) + 1e-5f);
#pragma unroll
        for (int oo = 0; oo < 8; oo++) h[oo] = (h[oo]-mu)*is*sg2[ob+oo] + sB2[ob+oo];
    }
    // ---- Linear 32->16 + GELU: my 4 outputs [lq*4, lq*4+4) ----
    float a2[4];
#pragma unroll
    for (int j = 0; j < 4; j++) a2[j] = sb2[lq*4+j];
#pragma unroll
    for (int r = 0; r < 4; r++) {
        float g[8];
#pragma unroll
        for (int s8 = 0; s8 < 8; s8++) g[s8] = __shfl(h[s8], r, 4);
#pragma unroll
        for (int j = 0; j < 4; j++)
#pragma unroll
            for (int s8 = 0; s8 < 8; s8++)
                a2[j] += sW2[(lq*4+j)*32 + r*8 + s8] * g[s8];
    }
    float h2[4];
#pragma unroll
    for (int j = 0; j < 4; j++) h2[j] = gelu_exact(a2[j]);

    // ---- Linear 16->1 (quad-reduced) ----
    float lgp = 0.f;
#pragma unroll
    for (int j = 0; j < 4; j++) lgp += sW3[lq*4+j] * h2[j];
    lgp += __shfl_xor(lgp, 1); lgp += __shfl_xor(lgp, 2);
    if (lq == 0) logits[i] = lgp + b3[0];
}

// ---------------- K3: per-edge gather softmax (grid exact: 24*256) ----------------
__global__ void __launch_bounds__(256) k_edge_softmax(
    const float* __restrict__ logits, const int* __restrict__ edge_cnt,
    const int* __restrict__ edge_bkt, float* __restrict__ out)
{
    int e = blockIdx.x * 256 + threadIdx.x;
    int n = min(edge_cnt[e], CAP_E);
    if (n == 0) return;
    const int4* bp = (const int4*)(edge_bkt + e * CAP_E);
    int4 b0 = bp[0], b1 = bp[1], b2 = bp[2], b3 = bp[3];
    int idx[16] = { b0.x,b0.y,b0.z,b0.w, b1.x,b1.y,b1.z,b1.w,
                    b2.x,b2.y,b2.z,b2.w, b3.x,b3.y,b3.z,b3.w };
    int i0 = b0.x;
    float lg[16];
#pragma unroll
    for (int u = 0; u < 16; u++) {
        int j = (u < n) ? idx[u] : i0;
        float val = logits[j];
        lg[u] = (u < n) ? val : -1e30f;
    }
    float mx = -1e30f;
#pragma unroll
    for (int u = 0; u < 16; u++) mx = fmaxf(mx, lg[u]);
    float ex[16], sum = 0.f;
#pragma unroll
    for (int u = 0; u < 16; u++) { ex[u] = expf(lg[u] - mx); sum += ex[u]; }
    float inv = 1.f / sum;
#pragma unroll
    for (int u = 0; u < 16; u++) if (u < n) out[idx[u]] = ex[u] * inv;
}

extern "C" void kernel_launch(void* const* d_in, const int* in_sizes, int n_in,
                              void* d_out, int out_size, void* d_ws, size_t ws_size,
                              hipStream_t stream) {
    const float* ef   = (const float*)d_in[0];
    const int*   eid  = (const int*)d_in[1];
    const int*   tri  = (const int*)d_in[2];
    const float* Wq   = (const float*)d_in[3];  const float* bq = (const float*)d_in[4];
    const float* Wk   = (const float*)d_in[5];  const float* bk = (const float*)d_in[6];
    const float* Wv   = (const float*)d_in[7];  const float* bv = (const float*)d_in[8];
    const float* W1   = (const float*)d_in[9];  const float* b1 = (const float*)d_in[10];
    const float* ln1g = (const float*)d_in[11]; const float* ln1b = (const float*)d_in[12];
    const float* rmsw = (const float*)d_in[13];
    const float* Wr   = (const float*)d_in[14]; const float* br = (const float*)d_in[15];
    const float* ln2g = (const float*)d_in[16]; const float* ln2b = (const float*)d_in[17];
    const float* W2   = (const float*)d_in[18]; const float* b2 = (const float*)d_in[19];
    const float* W3   = (const float*)d_in[20]; const float* b3 = (const float*)d_in[21];

    float* ws   = (float*)d_ws;
    float* kbuf = ws;                         // N_INC*8
    float* vbuf = kbuf + N_INC*8;             // N_INC*8
    float* logits = vbuf + N_INC*8;           // N_INC
    int* tri_cnt  = (int*)(logits + N_INC);   // N_TRI   } contiguous for
    int* edge_cnt = tri_cnt + N_TRI;          // N_EDGES } one memset
    int* tri_bkt  = edge_cnt + N_EDGES;       // N_TRI*CAP_T
    int* edge_bkt = tri_bkt + N_TRI*CAP_T;    // N_EDGES*CAP_E

    hipMemsetAsync(tri_cnt, 0, (size_t)(N_TRI + N_EDGES) * sizeof(int), stream);

    k_qkv_fill<<<48, 256, 0, stream>>>(ef, eid, tri, Wk, bk, Wv, bv,
                                       kbuf, vbuf,
                                       tri_cnt, tri_bkt, edge_cnt, edge_bkt);
    k_main<<<192, 256, 0, stream>>>(ef, kbuf, vbuf, tri, tri_cnt, tri_bkt,
                                    Wq, bq, W1, b1, ln1g, ln1b, rmsw, Wr, br,
                                    ln2g, ln2b, W2, b2, W3, b3, logits);
    k_edge_softmax<<<24, 256, 0, stream>>>(logits, edge_cnt, edge_bkt, (float*)d_out);
}